// Round 2
// baseline (599.526 us; speedup 1.0000x reference)
//
#include <hip/hip_runtime.h>
#include <hip/hip_bf16.h>
#include <cstdint>

// Problem constants (B=4, H=16, S=4096, D=64)
#define SEQ  4096
#define DIM  64
#define NBH  64     // B*H
#define NH   16
#define FEPS 1e-6f

// relu(sinh(x)): nonzero only for x>0 (sinh monotone odd, relu kills x<=0)
__device__ __forceinline__ float featmap(float x) {
    float ex = __expf(x);
    float sh = 0.5f * (ex - 1.0f / ex);
    return x > 0.0f ? sh : 0.0f;
}

// Phase 1: per (bh, chunk) block computes partial M[64][64] and ksum[64]
// over its S-chunk. Each wave holds a full M-partial in registers
// (lane = e, reg index = d), accumulating rank-1 updates via shfl broadcast.
__global__ __launch_bounds__(256) void k_phase1(
    const float* __restrict__ K, const float* __restrict__ V,
    const int* __restrict__ mask,        // numpy bool -> int32 in harness
    float* __restrict__ partM,
    int nchunk, int rows_per_chunk)
{
    const int chunk = blockIdx.x;
    const int bh    = blockIdx.y;
    const int b     = bh >> 4;            // H = 16
    const int tid   = threadIdx.x;
    const int wave  = tid >> 6;
    const int lane  = tid & 63;

    const float* Kb = K + (size_t)bh * SEQ * DIM;
    const float* Vb = V + (size_t)bh * SEQ * DIM;
    const int*   mb = mask + (size_t)b * SEQ;

    const int rpw = rows_per_chunk >> 2;  // rows per wave
    const int s0  = chunk * rows_per_chunk + wave * rpw;
    const int s1  = s0 + rpw;

    float acc[64];
    #pragma unroll
    for (int d = 0; d < 64; ++d) acc[d] = 0.0f;
    float ks = 0.0f;

    for (int s = s0; s < s1; ++s) {
        float kx = Kb[(size_t)s * DIM + lane];
        float v  = Vb[(size_t)s * DIM + lane];
        float kf = featmap(kx);
        kf = (mb[s] != 0) ? kf : 0.0f;    // mask padded keys
        ks += kf;
        #pragma unroll
        for (int d = 0; d < 64; ++d)
            acc[d] = fmaf(__shfl(kf, d), v, acc[d]);
    }

    // Cross-wave reduce: waves 0,1 store; waves 2,3 add; then fold pair.
    __shared__ float red[2][64][64];      // 32 KiB
    __shared__ float kred[2][64];

    if (wave < 2) {
        #pragma unroll
        for (int d = 0; d < 64; ++d) red[wave][d][lane] = acc[d];
        kred[wave][lane] = ks;
    }
    __syncthreads();
    if (wave >= 2) {
        #pragma unroll
        for (int d = 0; d < 64; ++d) red[wave - 2][d][lane] += acc[d];
        kred[wave - 2][lane] += ks;
    }
    __syncthreads();

    float* dst = partM + (size_t)(bh * nchunk + chunk) * 4160;
    const float* r = &red[0][0][0];
    for (int j = tid; j < 4096; j += 256)
        dst[j] = r[j] + r[4096 + j];
    if (tid < 64)
        dst[4096 + tid] = kred[0][tid] + kred[1][tid];
}

// Phase 1b: reduce chunk partials -> final M (4096) + ksum (64) per bh.
__global__ __launch_bounds__(256) void k_reduce(
    const float* __restrict__ partM, float* __restrict__ finalM, int nchunk)
{
    const int bh  = blockIdx.x;
    const int tid = threadIdx.x;
    const float* src = partM + (size_t)bh * nchunk * 4160;
    float* dst = finalM + (size_t)bh * 4160;
    for (int j = tid; j < 4160; j += 256) {
        float s = 0.0f;
        for (int c = 0; c < nchunk; ++c) s += src[(size_t)c * 4160 + j];
        dst[j] = s;
    }
}

// Phase 2: out[q][e] = (Qf[q] . M[:,e]) / max(Qf[q] . ksum, eps)
// Lane = e holds M[:,e] in 64 regs; qf broadcast via shfl.
__global__ __launch_bounds__(256) void k_phase2(
    const float* __restrict__ Q, const float* __restrict__ finalM,
    float* __restrict__ out)
{
    const int tile = blockIdx.x;          // 32 tiles of 128 rows
    const int bh   = blockIdx.y;
    const int tid  = threadIdx.x;
    const int wave = tid >> 6;
    const int lane = tid & 63;

    const float* Mb = finalM + (size_t)bh * 4160;
    float m[64];
    #pragma unroll
    for (int d = 0; d < 64; ++d) m[d] = Mb[d * 64 + lane];
    const float ksl = Mb[4096 + lane];

    const float* Qb = Q   + (size_t)bh * SEQ * DIM;
    float*       Ob = out + (size_t)bh * SEQ * DIM;

    const int q0 = tile * 128 + wave * 32;
    for (int q = q0; q < q0 + 32; ++q) {
        float qx = Qb[(size_t)q * DIM + lane];
        float qf = featmap(qx);

        // norm = sum_d qf[d] * ksum[d]  (lane plays the d role here)
        float np = qf * ksl;
        #pragma unroll
        for (int off = 32; off; off >>= 1) np += __shfl_xor(np, off);

        float a = 0.0f;
        #pragma unroll
        for (int d = 0; d < 64; ++d)
            a = fmaf(__shfl(qf, d), m[d], a);

        Ob[(size_t)q * DIM + lane] = a / fmaxf(np, FEPS);
    }
}

extern "C" void kernel_launch(void* const* d_in, const int* in_sizes, int n_in,
                              void* d_out, int out_size, void* d_ws, size_t ws_size,
                              hipStream_t stream) {
    const float* Q    = (const float*)d_in[0];
    const float* K    = (const float*)d_in[1];
    const float* V    = (const float*)d_in[2];
    const int*   mask = (const int*)d_in[3];   // numpy bool -> int32
    float* out = (float*)d_out;
    float* ws  = (float*)d_ws;

    // Adaptive chunk count so ws fits: partials (NBH*nchunk*4160) + final (NBH*4160)
    int nchunk = 16;
    while (nchunk > 1 &&
           ws_size < (size_t)(NBH * nchunk + NBH) * 4160 * sizeof(float))
        nchunk >>= 1;
    const int rows = SEQ / nchunk;

    float* partM  = ws;
    float* finalM = ws + (size_t)NBH * nchunk * 4160;

    dim3 gA(nchunk, NBH);
    k_phase1<<<gA, 256, 0, stream>>>(K, V, mask, partM, nchunk, rows);
    k_reduce<<<NBH, 256, 0, stream>>>(partM, finalM, nchunk);
    dim3 gC(32, NBH);
    k_phase2<<<gC, 256, 0, stream>>>(Q, finalM, out);
}

// Round 3
// 269.877 us; speedup vs baseline: 2.2215x; 2.2215x over previous
//
#include <hip/hip_runtime.h>
#include <hip/hip_bf16.h>
#include <cstdint>

#define SEQ  4096
#define DIM  64
#define NBH  64       // B*H
#define FEPS 1e-6f
#define MSTRIDE 4160  // 64*64 M + 64 ksum

typedef __attribute__((ext_vector_type(8))) short bf16x8;
typedef __attribute__((ext_vector_type(4))) float f32x4;

__device__ __forceinline__ float featmap(float x) {
    // relu(sinh(x)); sinh monotone odd so relu(sinh) = sinh(x) for x>0 else 0
    return x > 0.0f ? 0.5f * (__expf(x) - __expf(-x)) : 0.0f;
}

__device__ __forceinline__ unsigned short f2bf(float x) {
    // round-to-nearest-even fp32 -> bf16 (inputs finite, no NaN here)
    unsigned int u = __float_as_uint(x);
    u += 0x7fffu + ((u >> 16) & 1u);
    return (unsigned short)(u >> 16);
}

// ---------------------------------------------------------------------------
// Phase 1: per (chunk, bh) block: partial M[64][64] + ksum[64] over its
// S-chunk. LDS-staged tiles, 8x8 register tile per thread, no shfl.
// LDS rows padded to 68 words (272 B, 16B-aligned) -> conflict-free b128.
// ---------------------------------------------------------------------------
__global__ __launch_bounds__(256, 4) void k_phase1(
    const float* __restrict__ K, const float* __restrict__ V,
    const int* __restrict__ mask, float* __restrict__ partM,
    int nchunk, int rows_per_chunk)
{
    const int chunk = blockIdx.x;
    const int bh    = blockIdx.y;
    const int b     = bh >> 4;           // H = 16
    const int tid   = threadIdx.x;
    const int wave  = tid >> 6;
    const int lane  = tid & 63;
    const int ty    = lane >> 3;         // d-tile index (8 rows of M)
    const int tx    = lane & 7;          // e-tile index (8 cols of M)

    __shared__ __align__(16) float lds[8704];   // 34.8 KiB
    float* ldsK = lds;                   // [64][68]
    float* ldsV = lds + 4352;            // [64][68]

    const float* Kb = K + (size_t)bh * SEQ * DIM;
    const float* Vb = V + (size_t)bh * SEQ * DIM;
    const int*   mb = mask + (size_t)b * SEQ;

    float acc[8][8];
    #pragma unroll
    for (int i = 0; i < 8; ++i)
        #pragma unroll
        for (int j = 0; j < 8; ++j) acc[i][j] = 0.0f;
    float ks[8];
    #pragma unroll
    for (int i = 0; i < 8; ++i) ks[i] = 0.0f;

    const int srow = tid >> 2;           // staged row this thread loads
    const int sc   = tid & 3;            // 16-float column chunk
    const int nstage = rows_per_chunk >> 6;

    for (int stage = 0; stage < nstage; ++stage) {
        const int sb = chunk * rows_per_chunk + stage * 64;
        const int mrow = mb[sb + srow];
        const float4* krow = (const float4*)(Kb + (size_t)(sb + srow) * DIM);
        const float4* vrow = (const float4*)(Vb + (size_t)(sb + srow) * DIM);
        #pragma unroll
        for (int i = 0; i < 4; ++i) {
            float4 kq = krow[sc * 4 + i];
            float4 vq = vrow[sc * 4 + i];
            float4 kf;
            kf.x = mrow ? featmap(kq.x) : 0.0f;
            kf.y = mrow ? featmap(kq.y) : 0.0f;
            kf.z = mrow ? featmap(kq.z) : 0.0f;
            kf.w = mrow ? featmap(kq.w) : 0.0f;
            *(float4*)&ldsK[srow * 68 + sc * 16 + 4 * i] = kf;
            *(float4*)&ldsV[srow * 68 + sc * 16 + 4 * i] = vq;
        }
        __syncthreads();
        // waves interleave s: each staged row processed by exactly one wave
        for (int si = 0; si < 16; ++si) {
            const int s = si * 4 + wave;
            const float4 k0 = *(const float4*)&ldsK[s * 68 + ty * 8];
            const float4 k1 = *(const float4*)&ldsK[s * 68 + ty * 8 + 4];
            const float4 v0 = *(const float4*)&ldsV[s * 68 + tx * 8];
            const float4 v1 = *(const float4*)&ldsV[s * 68 + tx * 8 + 4];
            const float kf[8] = {k0.x,k0.y,k0.z,k0.w,k1.x,k1.y,k1.z,k1.w};
            const float vv[8] = {v0.x,v0.y,v0.z,v0.w,v1.x,v1.y,v1.z,v1.w};
            #pragma unroll
            for (int i = 0; i < 8; ++i) {
                ks[i] += kf[i];          // only tx==0 copy is consumed
                #pragma unroll
                for (int j = 0; j < 8; ++j)
                    acc[i][j] = fmaf(kf[i], vv[j], acc[i][j]);
            }
        }
        __syncthreads();
    }

    // Cross-wave fold (reuse lds): waves 0,1 write; waves 2,3 add.
    if (wave < 2) {
        float* rd = lds + wave * 4096;
        #pragma unroll
        for (int i = 0; i < 8; ++i) {
            *(float4*)&rd[(ty*8+i)*64 + tx*8]     = make_float4(acc[i][0],acc[i][1],acc[i][2],acc[i][3]);
            *(float4*)&rd[(ty*8+i)*64 + tx*8 + 4] = make_float4(acc[i][4],acc[i][5],acc[i][6],acc[i][7]);
        }
        if (tx == 0) {
            float* kr = lds + 8192 + wave * 64;
            #pragma unroll
            for (int i = 0; i < 8; ++i) kr[ty*8+i] = ks[i];
        }
    }
    __syncthreads();
    if (wave >= 2) {
        float* rd = lds + (wave - 2) * 4096;
        #pragma unroll
        for (int i = 0; i < 8; ++i)
            #pragma unroll
            for (int j = 0; j < 8; ++j)
                rd[(ty*8+i)*64 + tx*8 + j] += acc[i][j];
        if (tx == 0) {
            float* kr = lds + 8192 + (wave - 2) * 64;
            #pragma unroll
            for (int i = 0; i < 8; ++i) kr[ty*8+i] += ks[i];
        }
    }
    __syncthreads();

    float* dst = partM + (size_t)(bh * nchunk + chunk) * MSTRIDE;
    float4* dst4 = (float4*)dst;
    const float4* q0 = (const float4*)lds;
    const float4* q1 = (const float4*)(lds + 4096);
    #pragma unroll
    for (int t = 0; t < 4; ++t) {
        const int j = tid + t * 256;     // 1024 quads
        float4 a = q0[j], c = q1[j];
        dst4[j] = make_float4(a.x+c.x, a.y+c.y, a.z+c.z, a.w+c.w);
    }
    if (tid < 64) dst[4096 + tid] = lds[8192 + tid] + lds[8256 + tid];
}

// ---------------------------------------------------------------------------
// Phase 1b: reduce chunk partials -> final M + ksum per bh (vectorized).
// ---------------------------------------------------------------------------
__global__ __launch_bounds__(256) void k_reduce(
    const float* __restrict__ partM, float* __restrict__ finalM, int nchunk)
{
    const int bh  = blockIdx.x;
    const int tid = threadIdx.x;
    const float4* src = (const float4*)(partM + (size_t)bh * nchunk * MSTRIDE);
    float4* dst = (float4*)(finalM + (size_t)bh * MSTRIDE);
    for (int q = tid; q < MSTRIDE / 4; q += 256) {
        float4 s = src[q];
        for (int c = 1; c < nchunk; ++c) {
            float4 t = src[(size_t)c * (MSTRIDE / 4) + q];
            s.x += t.x; s.y += t.y; s.z += t.z; s.w += t.w;
        }
        dst[q] = s;
    }
}

// ---------------------------------------------------------------------------
// Phase 2: out[q][e] = (Qf[q] . M[:,e]) / max(Qf[q] . ksum, eps)
// bf16 MFMA 16x16x32: contraction dim d is memory-contiguous -> no transpose.
// Each wave: 16 q-rows x 64 e (4 n-tiles x 2 k-frags = 8 MFMAs). Z in fp32.
// ---------------------------------------------------------------------------
__global__ __launch_bounds__(256, 4) void k_phase2(
    const float* __restrict__ Q, const float* __restrict__ finalM,
    float* __restrict__ out)
{
    const int bh   = blockIdx.y;
    const int tid  = threadIdx.x;
    const int wave = tid >> 6;
    const int lane = tid & 63;
    const int r    = lane & 15;          // A row / B col / store col
    const int g    = lane >> 4;          // k-group

    const float* Mb = finalM + (size_t)bh * MSTRIDE;

    // B frags: lane holds M[kk*32 + g*8 + j][nt*16 + r]; ksum slices in fp32
    bf16x8 bfr[4][2];
    float  ksl[2][8];
    #pragma unroll
    for (int kk = 0; kk < 2; ++kk)
        #pragma unroll
        for (int j = 0; j < 8; ++j) {
            const int d = kk*32 + g*8 + j;
            ksl[kk][j] = Mb[4096 + d];
            #pragma unroll
            for (int nt = 0; nt < 4; ++nt)
                bfr[nt][kk][j] = (short)f2bf(Mb[d*64 + nt*16 + r]);
        }

    const int q0 = blockIdx.x * 64 + wave * 16;
    const float* Qrow = Q + (size_t)bh * SEQ * DIM + (size_t)(q0 + r) * DIM;

    // A frags (Qf) + fp32 norm partial
    bf16x8 afr[2];
    float z = 0.0f;
    #pragma unroll
    for (int kk = 0; kk < 2; ++kk) {
        float4 x0 = *(const float4*)(Qrow + kk*32 + g*8);
        float4 x1 = *(const float4*)(Qrow + kk*32 + g*8 + 4);
        const float qf[8] = {featmap(x0.x), featmap(x0.y), featmap(x0.z), featmap(x0.w),
                             featmap(x1.x), featmap(x1.y), featmap(x1.z), featmap(x1.w)};
        #pragma unroll
        for (int j = 0; j < 8; ++j) {
            z = fmaf(qf[j], ksl[kk][j], z);
            afr[kk][j] = (short)f2bf(qf[j]);
        }
    }
    // Z[row r] = sum over the 4 k-groups holding row r
    z += __shfl_xor(z, 16);
    z += __shfl_xor(z, 32);

    f32x4 acc[4];
    #pragma unroll
    for (int nt = 0; nt < 4; ++nt) acc[nt] = (f32x4){0.f, 0.f, 0.f, 0.f};
    #pragma unroll
    for (int kk = 0; kk < 2; ++kk)
        #pragma unroll
        for (int nt = 0; nt < 4; ++nt)
            acc[nt] = __builtin_amdgcn_mfma_f32_16x16x32_bf16(
                afr[kk], bfr[nt][kk], acc[nt], 0, 0, 0);

    // C layout: col = lane&15, row = (lane>>4)*4 + reg
    float rinv[4];
    #pragma unroll
    for (int j = 0; j < 4; ++j) {
        const float zc = __shfl(z, g*4 + j);   // lane idx < 16 holds Z[idx]
        rinv[j] = 1.0f / fmaxf(zc, FEPS);
    }
    float* Ob = out + (size_t)bh * SEQ * DIM;
    #pragma unroll
    for (int nt = 0; nt < 4; ++nt)
        #pragma unroll
        for (int j = 0; j < 4; ++j)
            Ob[(size_t)(q0 + g*4 + j) * DIM + nt*16 + r] = acc[nt][j] * rinv[j];
}

extern "C" void kernel_launch(void* const* d_in, const int* in_sizes, int n_in,
                              void* d_out, int out_size, void* d_ws, size_t ws_size,
                              hipStream_t stream) {
    const float* Q    = (const float*)d_in[0];
    const float* K    = (const float*)d_in[1];
    const float* V    = (const float*)d_in[2];
    const int*   mask = (const int*)d_in[3];   // numpy bool -> int32
    float* out = (float*)d_out;
    float* ws  = (float*)d_ws;

    int nchunk = 16;
    while (nchunk > 1 &&
           ws_size < (size_t)(NBH * nchunk + NBH) * MSTRIDE * sizeof(float))
        nchunk >>= 1;
    const int rows = SEQ / nchunk;

    float* partM  = ws;
    float* finalM = ws + (size_t)NBH * nchunk * MSTRIDE;

    k_phase1<<<dim3(nchunk, NBH), 256, 0, stream>>>(K, V, mask, partM, nchunk, rows);
    k_reduce<<<NBH, 256, 0, stream>>>(partM, finalM, nchunk);
    k_phase2<<<dim3(64, NBH), 256, 0, stream>>>(Q, finalM, out);
}

// Round 6
// 247.471 us; speedup vs baseline: 2.4226x; 1.0905x over previous
//
#include <hip/hip_runtime.h>
#include <hip/hip_bf16.h>
#include <cstdint>

#define SEQ  4096
#define DIM  64
#define NBH  64       // B*H
#define FEPS 1e-6f
#define MSTRIDE 4160  // 64*64 M + 64 ksum

typedef __attribute__((ext_vector_type(8))) short bf16x8;
typedef __attribute__((ext_vector_type(4))) float f32x4;

__device__ __forceinline__ float featmap(float x) {
    // relu(sinh(x)); sinh monotone odd so relu(sinh) = sinh(x) for x>0 else 0
    return x > 0.0f ? 0.5f * (__expf(x) - __expf(-x)) : 0.0f;
}

__device__ __forceinline__ short f2bf(float x) {
    // round-to-nearest-even fp32 -> bf16 (inputs finite, no NaN here)
    unsigned int u = __float_as_uint(x);
    u += 0x7fffu + ((u >> 16) & 1u);
    return (short)(u >> 16);
}

// ---------------------------------------------------------------------------
// Phase 1 (MFMA, no LDS): per (chunk, bh) block computes partial
// M[64][64] += Kf^T V over its S-chunk, plus ksum[64].
// Wave w owns d-rows [16w,16w+16); fragments loaded directly from global:
//   A[m=d][k=s] = Kf[s][16w+r]  (16 lanes x 4B contiguous per k-element)
//   B[k=s][n=e] = V[s][16nt+r]  (shared across waves -> L1/L2 hits)
// ---------------------------------------------------------------------------
__global__ __launch_bounds__(256, 4) void k_phase1(
    const float* __restrict__ K, const float* __restrict__ V,
    const int* __restrict__ mask, float* __restrict__ partM,
    int nchunk, int rows_per_chunk)
{
    const int chunk = blockIdx.x;
    const int bh    = blockIdx.y;
    const int b     = bh >> 4;           // H = 16
    const int tid   = threadIdx.x;
    const int wave  = tid >> 6;
    const int lane  = tid & 63;
    const int r     = lane & 15;         // fragment row/col
    const int g     = lane >> 4;         // k-group

    const float* Kb = K + (size_t)bh * SEQ * DIM;
    const float* Vb = V + (size_t)bh * SEQ * DIM;
    const int*   mb = mask + (size_t)b * SEQ;

    f32x4 acc[4];
    #pragma unroll
    for (int nt = 0; nt < 4; ++nt) acc[nt] = (f32x4){0.f, 0.f, 0.f, 0.f};
    float ksp = 0.0f;

    const int s0  = chunk * rows_per_chunk;
    const int nks = rows_per_chunk >> 5;

    for (int ks = 0; ks < nks; ++ks) {
        const int srow = s0 + ks * 32 + g * 8;
        const float* ka = Kb + (size_t)srow * DIM + wave * 16 + r;
        const float* va = Vb + (size_t)srow * DIM + r;
        const int*   ma = mb + srow;

        bf16x8 af;
        #pragma unroll
        for (int j = 0; j < 8; ++j) {
            float kf = featmap(ka[(size_t)j * DIM]);
            kf = ma[j] ? kf : 0.0f;      // mask padded keys
            ksp += kf;                   // fp32 ksum from pre-rounded kf
            af[j] = f2bf(kf);
        }

        bf16x8 bf[4];
        #pragma unroll
        for (int j = 0; j < 8; ++j)
            #pragma unroll
            for (int nt = 0; nt < 4; ++nt)
                bf[nt][j] = f2bf(va[(size_t)j * DIM + nt * 16]);

        #pragma unroll
        for (int nt = 0; nt < 4; ++nt)
            acc[nt] = __builtin_amdgcn_mfma_f32_16x16x32_bf16(
                af, bf[nt], acc[nt], 0, 0, 0);
    }

    // C layout: col = lane&15, row = (lane>>4)*4 + reg
    float* dst = partM + (size_t)(bh * nchunk + chunk) * MSTRIDE;
    #pragma unroll
    for (int nt = 0; nt < 4; ++nt)
        #pragma unroll
        for (int j = 0; j < 4; ++j)
            dst[(wave * 16 + g * 4 + j) * 64 + nt * 16 + r] = acc[nt][j];

    ksp += __shfl_xor(ksp, 16);          // fold the 4 k-groups
    ksp += __shfl_xor(ksp, 32);
    if (lane < 16) dst[4096 + wave * 16 + lane] = ksp;
}

// ---------------------------------------------------------------------------
// Phase 1b: reduce chunk partials -> final M + ksum per bh.
// Grid (4, NBH): 260 float4-quads per block -> all 256 CUs busy.
// ---------------------------------------------------------------------------
__global__ __launch_bounds__(256) void k_reduce(
    const float* __restrict__ partM, float* __restrict__ finalM, int nchunk)
{
    const int bh  = blockIdx.y;
    const int tid = threadIdx.x;
    const float4* src = (const float4*)(partM + (size_t)bh * nchunk * MSTRIDE);
    float4* dst = (float4*)(finalM + (size_t)bh * MSTRIDE);
    const int qend = blockIdx.x * 260 + 260;
    for (int q = blockIdx.x * 260 + tid; q < qend; q += 256) {
        float4 s = src[q];
        for (int c = 1; c < nchunk; ++c) {
            float4 t = src[(size_t)c * (MSTRIDE / 4) + q];
            s.x += t.x; s.y += t.y; s.z += t.z; s.w += t.w;
        }
        dst[q] = s;
    }
}

// ---------------------------------------------------------------------------
// Phase 2: out[q][e] = (Qf[q] . M[:,e]) / max(Qf[q] . ksum, eps)
// bf16 MFMA 16x16x32; contraction dim d is memory-contiguous for Q.
// ---------------------------------------------------------------------------
__global__ __launch_bounds__(256, 4) void k_phase2(
    const float* __restrict__ Q, const float* __restrict__ finalM,
    float* __restrict__ out)
{
    const int bh   = blockIdx.y;
    const int tid  = threadIdx.x;
    const int wave = tid >> 6;
    const int lane = tid & 63;
    const int r    = lane & 15;          // A row / B col / store col
    const int g    = lane >> 4;          // k-group

    const float* Mb = finalM + (size_t)bh * MSTRIDE;

    // B frags: lane holds M[kk*32 + g*8 + j][nt*16 + r]; ksum slices in fp32
    bf16x8 bfr[4][2];
    float  ksl[2][8];
    #pragma unroll
    for (int kk = 0; kk < 2; ++kk)
        #pragma unroll
        for (int j = 0; j < 8; ++j) {
            const int d = kk*32 + g*8 + j;
            ksl[kk][j] = Mb[4096 + d];
            #pragma unroll
            for (int nt = 0; nt < 4; ++nt)
                bfr[nt][kk][j] = f2bf(Mb[d*64 + nt*16 + r]);
        }

    const int q0 = blockIdx.x * 64 + wave * 16;
    const float* Qrow = Q + (size_t)bh * SEQ * DIM + (size_t)(q0 + r) * DIM;

    // A frags (Qf) + fp32 norm partial
    bf16x8 afr[2];
    float z = 0.0f;
    #pragma unroll
    for (int kk = 0; kk < 2; ++kk) {
        float4 x0 = *(const float4*)(Qrow + kk*32 + g*8);
        float4 x1 = *(const float4*)(Qrow + kk*32 + g*8 + 4);
        const float qf[8] = {featmap(x0.x), featmap(x0.y), featmap(x0.z), featmap(x0.w),
                             featmap(x1.x), featmap(x1.y), featmap(x1.z), featmap(x1.w)};
        #pragma unroll
        for (int j = 0; j < 8; ++j) {
            z = fmaf(qf[j], ksl[kk][j], z);
            afr[kk][j] = f2bf(qf[j]);
        }
    }
    // Z[row r] = sum over the 4 k-groups holding row r
    z += __shfl_xor(z, 16);
    z += __shfl_xor(z, 32);

    f32x4 acc[4];
    #pragma unroll
    for (int nt = 0; nt < 4; ++nt) acc[nt] = (f32x4){0.f, 0.f, 0.f, 0.f};
    #pragma unroll
    for (int kk = 0; kk < 2; ++kk)
        #pragma unroll
        for (int nt = 0; nt < 4; ++nt)
            acc[nt] = __builtin_amdgcn_mfma_f32_16x16x32_bf16(
                afr[kk], bfr[nt][kk], acc[nt], 0, 0, 0);

    // C layout: col = lane&15, row = (lane>>4)*4 + reg
    float rinv[4];
    #pragma unroll
    for (int j = 0; j < 4; ++j) {
        const float zc = __shfl(z, g*4 + j);   // lane idx < 16 holds Z[idx]
        rinv[j] = 1.0f / fmaxf(zc, FEPS);
    }
    float* Ob = out + (size_t)bh * SEQ * DIM;
    #pragma unroll
    for (int nt = 0; nt < 4; ++nt)
        #pragma unroll
        for (int j = 0; j < 4; ++j)
            Ob[(size_t)(q0 + g*4 + j) * DIM + nt*16 + r] = acc[nt][j] * rinv[j];
}

extern "C" void kernel_launch(void* const* d_in, const int* in_sizes, int n_in,
                              void* d_out, int out_size, void* d_ws, size_t ws_size,
                              hipStream_t stream) {
    const float* Q    = (const float*)d_in[0];
    const float* K    = (const float*)d_in[1];
    const float* V    = (const float*)d_in[2];
    const int*   mask = (const int*)d_in[3];   // numpy bool -> int32
    float* out = (float*)d_out;
    float* ws  = (float*)d_ws;

    int nchunk = 16;
    while (nchunk > 1 &&
           ws_size < (size_t)(NBH * nchunk + NBH) * MSTRIDE * sizeof(float))
        nchunk >>= 1;
    const int rows = SEQ / nchunk;

    float* partM  = ws;
    float* finalM = ws + (size_t)NBH * nchunk * MSTRIDE;

    k_phase1<<<dim3(nchunk, NBH), 256, 0, stream>>>(K, V, mask, partM, nchunk, rows);
    k_reduce<<<dim3(4, NBH), 256, 0, stream>>>(partM, finalM, nchunk);
    k_phase2<<<dim3(64, NBH), 256, 0, stream>>>(Q, finalM, out);
}